// Round 4
// baseline (396.173 us; speedup 1.0000x reference)
//
#include <hip/hip_runtime.h>

#define L_ 2
#define MODS_ 3
#define D_ 512
#define R_ 32
#define B_ 16
#define T_ 512
#define BT_ (B_*T_)   /* 8192 tokens per modality */
#define BETA_ 0.1f

typedef _Float16 h8 __attribute__((ext_vector_type(8)));
typedef __fp16   fp16x2 __attribute__((ext_vector_type(2)));
typedef float f32x16 __attribute__((ext_vector_type(16)));

__device__ __forceinline__ h8 mk_h8(float f0,float f1,float f2,float f3,
                                    float f4,float f5,float f6,float f7){
    union { h8 v; fp16x2 p[4]; } r;
    r.p[0] = __builtin_amdgcn_cvt_pkrtz(f0,f1);
    r.p[1] = __builtin_amdgcn_cvt_pkrtz(f2,f3);
    r.p[2] = __builtin_amdgcn_cvt_pkrtz(f4,f5);
    r.p[3] = __builtin_amdgcn_cvt_pkrtz(f6,f7);
    return r.v;
}

__device__ __forceinline__ float h2f(unsigned short x){
    return (float)__builtin_bit_cast(_Float16, x);
}
__device__ __forceinline__ unsigned short f2h(float x){
    return __builtin_bit_cast(unsigned short, (_Float16)x);
}

// ---------------------------------------------------------------------------
// k_cvt: weights -> fragment-major f16 (unchanged layouts).
// WattF frag: per (li,j): [s:32][nb:16][kh:2][lane:64][j8:8]
//   elem = Watt[ko = s*32 + kh*16 + (lane>>5)*8 + j8][nb*32 + (lane&31)]
// WprojF frag: per (li,m): [s:32][nb:4][lane:64][j8:8], cols = [q1|k1|q2|k2]
//   elem = Wsel(nb)[k = s*16 + (lane>>5)*8 + j8][lane&31]
// ---------------------------------------------------------------------------
__global__ __launch_bounds__(256) void k_cvt(
    const float* __restrict__ Watt,
    const float* __restrict__ Wq1, const float* __restrict__ Wk1,
    const float* __restrict__ Wq2, const float* __restrict__ Wk2,
    uint4* __restrict__ WattF, uint4* __restrict__ WprojF)
{
    const int t = blockIdx.x*256 + threadIdx.x;
    const int NWATT = 6*32*16*2*64;   // 393216 (frag,lane) units
    if (t < NWATT) {
        const int lane = t & 63, f = t >> 6;
        const int kh = f & 1, nb = (f>>1)&15, s = (f>>5)&31, lj = f>>10;
        const int col  = nb*32 + (lane&31);
        const int row0 = s*32 + kh*16 + (lane>>5)*8;
        const float* src = Watt + ((size_t)lj*1024)*D_ + col;
        union { uint4 q; unsigned short us[8]; } o;
        #pragma unroll
        for (int i=0;i<8;i++) o.us[i] = f2h(src[(size_t)(row0+i)*D_]);
        WattF[t] = o.q;
    } else {
        const int t2 = t - NWATT;           // < 49152
        const int lane = t2 & 63, f = t2 >> 6;
        const int nb = f & 3, s = (f>>2)&31, lm = f>>7;
        const float* Ws = (nb==0)?Wq1:(nb==1)?Wk1:(nb==2)?Wq2:Wk2;
        const int r  = lane&31;
        const int k0 = s*16 + (lane>>5)*8;
        const float* src = Ws + ((size_t)lm*D_)*R_ + r;
        union { uint4 q; unsigned short us[8]; } o;
        #pragma unroll
        for (int i=0;i<8;i++) o.us[i] = f2h(src[(size_t)(k0+i)*R_]);
        WprojF[t2] = o.q;
    }
}

// ---------------------------------------------------------------------------
// k_proj_mfma v2: barrier-free, LDS-free. B-frags direct to VGPR (dbuf).
// [q1|k1|q2|k2] = X @ Wcat (f16 MFMA); U16 = 64*q1*k1, V16 = 64*q2*k2 (f16).
// 4 waves = (tokg 0/1) x (colh 0/1). grid (BT/64, MODS), block 256.
// ---------------------------------------------------------------------------
__global__ __launch_bounds__(256) void k_proj_mfma(
    const float* __restrict__ xa, const float* __restrict__ xt,
    const float* __restrict__ xv, const float* __restrict__ X,
    const uint4* __restrict__ WprojF,
    const float* __restrict__ bq1, const float* __restrict__ bq2,
    const float* __restrict__ bk1, const float* __restrict__ bk2,
    unsigned short* __restrict__ U16, unsigned short* __restrict__ V16, int li)
{
    const int tid = threadIdx.x;
    const int wid = tid>>6, lane = tid&63;
    const int lh = lane>>5, lr = lane&31;
    const int tokg = wid&1, colh = wid>>1;
    const int m = blockIdx.y;
    const int tok0 = blockIdx.x*64;
    const int lm = li*MODS_ + m;
    const int t = tok0 + tokg*32 + lr;

    const float* Xbase = (li==0) ? (m==0?xa:(m==1?xt:xv)) : (X + (size_t)m*BT_*D_);
    const float* Xrow  = Xbase + (size_t)t*D_;
    const uint4* src   = WprojF + (size_t)lm*8192 + (colh*2)*64 + lane;

    f32x16 acc0, acc1;
    #pragma unroll
    for (int i=0;i<16;i++){ acc0[i]=0.f; acc1[i]=0.f; }

    uint4 bc0 = src[0], bc1 = src[64];
    uint4 bn0, bn1;
    float4 x0 = *(const float4*)&Xrow[lh*8];
    float4 x1 = *(const float4*)&Xrow[lh*8+4];
    float4 nx0, nx1;

    #pragma unroll
    for (int s=0;s<32;s++){
        if (s<31){
            bn0 = src[(s+1)*256];
            bn1 = src[(s+1)*256 + 64];
            nx0 = *(const float4*)&Xrow[(s+1)*16 + lh*8];
            nx1 = *(const float4*)&Xrow[(s+1)*16 + lh*8 + 4];
        }
        h8 a = mk_h8(x0.x,x0.y,x0.z,x0.w, x1.x,x1.y,x1.z,x1.w);
        acc0 = __builtin_amdgcn_mfma_f32_32x32x16_f16(a, __builtin_bit_cast(h8,bc0), acc0, 0,0,0);
        acc1 = __builtin_amdgcn_mfma_f32_32x32x16_f16(a, __builtin_bit_cast(h8,bc1), acc1, 0,0,0);
        if (s<31){ bc0=bn0; bc1=bn1; x0=nx0; x1=nx1; }
    }

    const float bA = (colh==0 ? bq1 : bq2)[lm*R_ + lr];
    const float bB = (colh==0 ? bk1 : bk2)[lm*R_ + lr];
    unsigned short* Out = (colh==0 ? U16 : V16);
    #pragma unroll
    for (int reg=0;reg<16;reg++){
        const int row = (reg&3) + 8*(reg>>2) + 4*lh;
        const int tt  = tok0 + tokg*32 + row;
        const float val = (acc0[reg]+bA)*(acc1[reg]+bB)*64.f;
        Out[((size_t)m*BT_ + tt)*R_ + lr] = f2h(val);
    }
}

// ---------------------------------------------------------------------------
// k_mqk_part: partial Mqk over a 64-token slice.
// Mqk_part[p][mb][k][l] = sum_{t in slice} U16[t,k]*V16[t,l]  (scale 4096)
// grid (48, 8), block 256.
// ---------------------------------------------------------------------------
__global__ __launch_bounds__(256) void k_mqk_part(
    const unsigned short* __restrict__ U16,
    const unsigned short* __restrict__ V16,
    float* __restrict__ Mqp)
{
    const int tid = threadIdx.x;
    const int mb  = blockIdx.x;
    const int p   = blockIdx.y;
    const int t0  = p*64;

    __shared__ unsigned short Us[64][32];
    __shared__ unsigned short Vs[64][32];

    const int srow = tid>>2, sq = (tid&3)*8;
    const size_t base = (size_t)mb*T_*R_ + (size_t)(t0+srow)*R_ + sq;
    *(uint4*)&Us[srow][sq] = *(const uint4*)&U16[base];
    *(uint4*)&Vs[srow][sq] = *(const uint4*)&V16[base];
    __syncthreads();

    const int l = tid & 31;
    const int g = tid >> 5;
    float acc[4] = {0.f,0.f,0.f,0.f};
    #pragma unroll 8
    for (int tt=0; tt<64; ++tt){
        const float vv = h2f(Vs[tt][l]);
        #pragma unroll
        for (int i=0;i<4;i++) acc[i] += h2f(Us[tt][g+8*i]) * vv;
    }
    float* out = Mqp + ((size_t)p*48 + mb)*1024;
    #pragma unroll
    for (int i=0;i<4;i++) out[(g+8*i)*R_ + l] = acc[i];
}

// ---------------------------------------------------------------------------
// k_pmat v2: reduce 8 partials (and undo 4096*T scale), then P = Ma @ Mc.
// grid (MODS_, B_), block 256.
// ---------------------------------------------------------------------------
__global__ __launch_bounds__(256) void k_pmat(const float* __restrict__ Mqp,
                                              float* __restrict__ P)
{
    const int tid = threadIdx.x;
    const int j = blockIdx.x, b = blockIdx.y;
    const int a = (j == 0) ? 1 : 0;
    const int c = (j == 2) ? 1 : 2;
    const float sc = 1.0f/(4096.0f*(float)T_);

    __shared__ float As[32][32];
    __shared__ float Cs[32][32];

    float4 sa = {0,0,0,0}, scv = {0,0,0,0};
    #pragma unroll
    for (int p=0;p<8;p++){
        const float4 pa = *(const float4*)&Mqp[((size_t)p*48 + a*B_+b)*1024 + tid*4];
        const float4 pc = *(const float4*)&Mqp[((size_t)p*48 + c*B_+b)*1024 + tid*4];
        sa.x+=pa.x; sa.y+=pa.y; sa.z+=pa.z; sa.w+=pa.w;
        scv.x+=pc.x; scv.y+=pc.y; scv.z+=pc.z; scv.w+=pc.w;
    }
    sa.x*=sc; sa.y*=sc; sa.z*=sc; sa.w*=sc;
    scv.x*=sc; scv.y*=sc; scv.z*=sc; scv.w*=sc;
    *(float4*)&(((float*)As)[tid*4]) = sa;
    *(float4*)&(((float*)Cs)[tid*4]) = scv;
    __syncthreads();

    const int o = tid & 31, g = tid >> 5;
    float acc[4] = {0.f,0.f,0.f,0.f};
    #pragma unroll
    for (int l = 0; l < 32; ++l) {
        const float cvv = Cs[l][o];
        #pragma unroll
        for (int i = 0; i < 4; ++i) acc[i] += As[g + 8*i][l] * cvv;
    }
    #pragma unroll
    for (int i = 0; i < 4; ++i)
        P[((size_t)(j*B_ + b))*1024 + (size_t)(g + 8*i)*R_ + o] = acc[i];
}

// ---------------------------------------------------------------------------
// k_wvec v2: W16[t,o] = sum_l V16[t,l] * P[l,o]  (keeps the 64x scale)
// grid (BT/128, MODS), block 256.
// ---------------------------------------------------------------------------
__global__ __launch_bounds__(256) void k_wvec(
    const unsigned short* __restrict__ V16,
    const float* __restrict__ P,
    unsigned short* __restrict__ W16)
{
    const int tid  = threadIdx.x;
    const int m    = blockIdx.y;
    const int tok0 = blockIdx.x * 128;
    const int b    = tok0 / T_;

    __shared__ float Ps[32][32];
    __shared__ unsigned short Vs[128][32];

    *(float4*)&(((float*)Ps)[tid*4]) =
        *(const float4*)&P[((size_t)(m*B_ + b))*1024 + tid*4];

    const unsigned short* Vb = V16 + ((size_t)m*BT_ + tok0)*R_;
    #pragma unroll
    for (int e=0;e<2;e++){
        const int k = tid*2 + e;
        *(uint4*)&Vs[k>>2][(k&3)*8] = *(const uint4*)&Vb[(size_t)(k>>2)*R_ + (k&3)*8];
    }
    __syncthreads();

    const int o = tid & 31, g = tid >> 5;
    unsigned short* Wb = W16 + ((size_t)m*BT_ + tok0)*R_;
    #pragma unroll
    for (int i = 0; i < 16; ++i) {
        const int t = g*16 + i;
        float acc = 0.f;
        #pragma unroll
        for (int l = 0; l < 32; ++l) acc += h2f(Vs[t][l]) * Ps[l][o];
        Wb[(size_t)t*R_ + o] = f2h(acc);
    }
}

// ---------------------------------------------------------------------------
// k_gemm2_mfma v2: barrier-free, LDS-free. A = (64u)(64w) via v_pk_mul_f16;
// B-frags direct to VGPR, ping-pong double buffer. acc scaled by 2^-12.
// 4 waves = (tokg 0/1) x (colg 0/1, 128 cols each). K = 1024 = 32 steps.
// grid (BT/64, D/256, MODS), block 256.
// ---------------------------------------------------------------------------
__global__ __launch_bounds__(256) void k_gemm2_mfma(
    const unsigned short* __restrict__ U16,
    const unsigned short* __restrict__ W16,
    const uint4* __restrict__ WattF, const float* __restrict__ batt,
    const float* __restrict__ xa, const float* __restrict__ xt,
    const float* __restrict__ xv,
    float* __restrict__ X, int li)
{
    const int tid = threadIdx.x;
    const int wid = tid>>6, lane = tid&63;
    const int lh = lane>>5, lr = lane&31;
    const int tokg = wid&1, colg = wid>>1;
    const int j = blockIdx.z;
    const int tok0 = blockIdx.x*64;
    const int nbB = blockIdx.y*8;
    const int t = tok0 + tokg*32 + lr;

    // per-lane base into frag-major Watt: [s][nb:16][kh:2][lane:64]
    const uint4* src = WattF + (size_t)(li*MODS_ + j)*65536
                             + (size_t)(nbB + colg*4)*128 + lane;

    // u (32 f16) and w fragments (2x8 f16) for this lane's token
    union { uint4 q[4]; __fp16 h[32]; } uu;
    {
        const uint4* Ur = (const uint4*)(U16 + ((size_t)j*BT_ + t)*R_);
        uu.q[0]=Ur[0]; uu.q[1]=Ur[1]; uu.q[2]=Ur[2]; uu.q[3]=Ur[3];
    }
    union { uint4 q; fp16x2 p[4]; } wa, wb;
    {
        const uint4* Wr = (const uint4*)(W16 + ((size_t)j*BT_ + t)*R_);
        wa.q = Wr[lh];      // f16 cols lh*8 .. +8
        wb.q = Wr[2+lh];    // f16 cols 16+lh*8 .. +8
    }

    f32x16 acc[4];
    #pragma unroll
    for (int n=0;n<4;n++){
        #pragma unroll
        for (int i=0;i<16;i++) acc[n][i]=0.f;
    }

    uint4 bufA[8], bufB[8];
    #pragma unroll
    for (int f=0;f<8;f++) bufA[f] = src[(f>>1)*128 + (f&1)*64];

    #pragma unroll
    for (int s2=0; s2<16; ++s2){
        const int s = 2*s2;
        // prefetch s+1 into bufB
        #pragma unroll
        for (int f=0;f<8;f++) bufB[f] = src[(size_t)(s+1)*2048 + (f>>1)*128 + (f&1)*64];
        // compute step s from bufA
        {
            fp16x2 us2; us2[0] = uu.h[s]; us2[1] = uu.h[s];
            union { h8 v; fp16x2 p[4]; } a0, a1;
            #pragma unroll
            for (int q=0;q<4;q++){ a0.p[q] = us2*wa.p[q]; a1.p[q] = us2*wb.p[q]; }
            #pragma unroll
            for (int n=0;n<4;n++){
                acc[n] = __builtin_amdgcn_mfma_f32_32x32x16_f16(a0.v, __builtin_bit_cast(h8,bufA[2*n  ]), acc[n], 0,0,0);
                acc[n] = __builtin_amdgcn_mfma_f32_32x32x16_f16(a1.v, __builtin_bit_cast(h8,bufA[2*n+1]), acc[n], 0,0,0);
            }
        }
        // prefetch s+2 into bufA
        if (s+2 < 32){
            #pragma unroll
            for (int f=0;f<8;f++) bufA[f] = src[(size_t)(s+2)*2048 + (f>>1)*128 + (f&1)*64];
        }
        // compute step s+1 from bufB
        {
            fp16x2 us2; us2[0] = uu.h[s+1]; us2[1] = uu.h[s+1];
            union { h8 v; fp16x2 p[4]; } a0, a1;
            #pragma unroll
            for (int q=0;q<4;q++){ a0.p[q] = us2*wa.p[q]; a1.p[q] = us2*wb.p[q]; }
            #pragma unroll
            for (int n=0;n<4;n++){
                acc[n] = __builtin_amdgcn_mfma_f32_32x32x16_f16(a0.v, __builtin_bit_cast(h8,bufB[2*n  ]), acc[n], 0,0,0);
                acc[n] = __builtin_amdgcn_mfma_f32_32x32x16_f16(a1.v, __builtin_bit_cast(h8,bufB[2*n+1]), acc[n], 0,0,0);
            }
        }
    }

    // epilogue: unscale, bias, residual
    const float* battp = batt + (size_t)(li*MODS_ + j)*D_;
    const float* Xin = (li==0) ? (j==0?xa:(j==1?xt:xv)) : (X + (size_t)j*BT_*D_);
    float* Xout = X + (size_t)j*BT_*D_;
    const float inv = 1.0f/4096.0f;
    #pragma unroll
    for (int n=0;n<4;n++){
        const int d  = (nbB + colg*4 + n)*32 + lr;
        const float bt = battp[d];
        #pragma unroll
        for (int reg=0; reg<16; ++reg){
            const int row = (reg&3) + 8*(reg>>2) + 4*lh;
            const size_t xi = (size_t)(tok0 + tokg*32 + row)*D_ + d;
            const float xvv = Xin[xi];
            Xout[xi] = (acc[n][reg]*inv + bt)*xvv + BETA_*xvv;
        }
    }
}

// ---------------------------------------------------------------------------
extern "C" void kernel_launch(void* const* d_in, const int* in_sizes, int n_in,
                              void* d_out, int out_size, void* d_ws, size_t ws_size,
                              hipStream_t stream)
{
    const float* x_a  = (const float*)d_in[0];
    const float* x_t  = (const float*)d_in[1];
    const float* x_v  = (const float*)d_in[2];
    const float* Wq1  = (const float*)d_in[3];
    const float* bq1  = (const float*)d_in[4];
    const float* Wq2  = (const float*)d_in[5];
    const float* bq2  = (const float*)d_in[6];
    const float* Wk1  = (const float*)d_in[7];
    const float* bk1  = (const float*)d_in[8];
    const float* Wk2  = (const float*)d_in[9];
    const float* bk2  = (const float*)d_in[10];
    const float* Watt = (const float*)d_in[11];
    const float* batt = (const float*)d_in[12];

    float* X = (float*)d_out;                        // [3][B*T][D]

    uint4* WattF  = (uint4*)d_ws;                    // 393216 u4 (6 MB)
    uint4* WprojF = WattF + 393216;                  // 49152 u4 (768 KB)
    float* Mqp    = (float*)(WprojF + 49152);        // 8*48*1024 f32 (1.5 MB)
    float* P      = Mqp + 393216;                    // 48*1024 f32
    unsigned short* U16 = (unsigned short*)(P + 49152);   // 3*BT*32 f16 (1.5 MB)
    unsigned short* V16 = U16 + (size_t)MODS_*BT_*R_;
    unsigned short* W16 = V16 + (size_t)MODS_*BT_*R_;

    k_cvt<<<1728, 256, 0, stream>>>(Watt, Wq1, Wk1, Wq2, Wk2, WattF, WprojF);

    for (int li = 0; li < L_; ++li) {
        k_proj_mfma<<<dim3(BT_/64, MODS_), 256, 0, stream>>>(
            x_a, x_t, x_v, X, WprojF, bq1, bq2, bk1, bk2, U16, V16, li);
        k_mqk_part<<<dim3(MODS_*B_, 8), 256, 0, stream>>>(U16, V16, Mqp);
        k_pmat<<<dim3(MODS_, B_), 256, 0, stream>>>(Mqp, P);
        k_wvec<<<dim3(BT_/128, MODS_), 256, 0, stream>>>(V16, P, W16);
        k_gemm2_mfma<<<dim3(BT_/64, D_/256, MODS_), 256, 0, stream>>>(
            U16, W16, WattF, batt, x_a, x_t, x_v, X, li);
    }
}

// Round 7
// 287.619 us; speedup vs baseline: 1.3774x; 1.3774x over previous
//
#include <hip/hip_runtime.h>

#define L_ 2
#define MODS_ 3
#define D_ 512
#define R_ 32
#define B_ 16
#define T_ 512
#define BT_ (B_*T_)   /* 8192 tokens per modality */
#define BETA_ 0.1f

typedef _Float16 h8 __attribute__((ext_vector_type(8)));
typedef __fp16   fp16x2 __attribute__((ext_vector_type(2)));
typedef float f32x16 __attribute__((ext_vector_type(16)));

typedef __attribute__((address_space(3))) unsigned int lds_u32;
typedef __attribute__((address_space(1))) const unsigned int glb_u32;

__device__ __forceinline__ void gload_lds16(const uint4* gsrc, uint4* ldst){
    __builtin_amdgcn_global_load_lds((glb_u32*)gsrc, (lds_u32*)ldst, 16, 0, 0);
}

#define WAITVM(N) asm volatile("s_waitcnt vmcnt(" #N ")" ::: "memory")
#define SBAR() __builtin_amdgcn_s_barrier()

__device__ __forceinline__ h8 mk_h8(float f0,float f1,float f2,float f3,
                                    float f4,float f5,float f6,float f7){
    union { h8 v; fp16x2 p[4]; } r;
    r.p[0] = __builtin_amdgcn_cvt_pkrtz(f0,f1);
    r.p[1] = __builtin_amdgcn_cvt_pkrtz(f2,f3);
    r.p[2] = __builtin_amdgcn_cvt_pkrtz(f4,f5);
    r.p[3] = __builtin_amdgcn_cvt_pkrtz(f6,f7);
    return r.v;
}
__device__ __forceinline__ float h2f(unsigned short x){
    return (float)__builtin_bit_cast(_Float16, x);
}
__device__ __forceinline__ unsigned short f2h(float x){
    return __builtin_bit_cast(unsigned short, (_Float16)x);
}

// ---------------------------------------------------------------------------
// k_cvt: weights -> fragment-major f16 (layouts unchanged).
// WattF per (li,j): [s:32][nb:16][kh:2][lane:64] u4;
//   elem = Watt[s*32 + kh*16 + (lane>>5)*8 + j8][nb*32 + (lane&31)]
// WprojF per (li,m): [s:32][nb:4][lane:64] u4, nb = [q1|k1|q2|k2]
//   elem = Wsel(nb)[s*16 + (lane>>5)*8 + j8][lane&31]
// ---------------------------------------------------------------------------
__global__ __launch_bounds__(256) void k_cvt(
    const float* __restrict__ Watt,
    const float* __restrict__ Wq1, const float* __restrict__ Wk1,
    const float* __restrict__ Wq2, const float* __restrict__ Wk2,
    uint4* __restrict__ WattF, uint4* __restrict__ WprojF)
{
    const int t = blockIdx.x*256 + threadIdx.x;
    const int NWATT = 6*32*16*2*64;   // 393216
    if (t < NWATT) {
        const int lane = t & 63, f = t >> 6;
        const int kh = f & 1, nb = (f>>1)&15, s = (f>>5)&31, lj = f>>10;
        const int col  = nb*32 + (lane&31);
        const int row0 = s*32 + kh*16 + (lane>>5)*8;
        const float* src = Watt + ((size_t)lj*1024)*D_ + col;
        union { uint4 q; unsigned short us[8]; } o;
        #pragma unroll
        for (int i=0;i<8;i++) o.us[i] = f2h(src[(size_t)(row0+i)*D_]);
        WattF[t] = o.q;
    } else {
        const int t2 = t - NWATT;           // < 49152
        const int lane = t2 & 63, f = t2 >> 6;
        const int nb = f & 3, s = (f>>2)&31, lm = f>>7;
        const float* Ws = (nb==0)?Wq1:(nb==1)?Wk1:(nb==2)?Wq2:Wk2;
        const int r  = lane&31;
        const int k0 = s*16 + (lane>>5)*8;
        const float* src = Ws + ((size_t)lm*D_)*R_ + r;
        union { uint4 q; unsigned short us[8]; } o;
        #pragma unroll
        for (int i=0;i<8;i++) o.us[i] = f2h(src[(size_t)(k0+i)*R_]);
        WprojF[t2] = o.q;
    }
}

// ---------------------------------------------------------------------------
// k_proj_mfma v3: counted-vmcnt 4-deep pipeline.
// Block: 64 tok x 128 cols. 4 waves = (wtok 0/1) x (pair 0/1: {q1,k1} / {q2,k2})
// K-step 32 (2 MFMA-K16 per proj). 16 steps. Stage = 8 KB (2 gload insts/wave).
// U16 = 64*q1*k1 (f16), V16 = 64*q2*k2.
// grid (BT/64=128, MODS), block 256
// ---------------------------------------------------------------------------
__global__ __launch_bounds__(256) void k_proj_mfma(
    const float* __restrict__ xa, const float* __restrict__ xt,
    const float* __restrict__ xv, const float* __restrict__ X,
    const uint4* __restrict__ WprojF,
    const float* __restrict__ bq1, const float* __restrict__ bq2,
    const float* __restrict__ bk1, const float* __restrict__ bk2,
    unsigned short* __restrict__ U16, unsigned short* __restrict__ V16, int li)
{
    __shared__ uint4 sm[4][512];      // 4 x 8KB
    const int tid = threadIdx.x;
    const int wid = tid>>6, lane = tid&63;
    const int lh = lane>>5, lr = lane&31;
    const int wtok = wid&1, pair = wid>>1;
    const int m = blockIdx.y;
    const int tok0 = blockIdx.x*64;
    const int lm = li*MODS_ + m;
    const int t = tok0 + wtok*32 + lr;

    const float* Xbase = (li==0) ? (m==0?xa:(m==1?xt:xv)) : (X + (size_t)m*BT_*D_);
    const float* Xrow  = Xbase + (size_t)t*D_;
    const uint4* srcp  = WprojF + (size_t)lm*8192;

    f32x16 accQ, accK;
    #pragma unroll
    for (int i=0;i<16;i++){ accQ[i]=0.f; accK[i]=0.f; }

    float4 xr[2][2][2];   // [parity][kst][half] — indices compile-time after unroll

#define PJ_XLOAD(T) do{ \
        xr[(T)&1][0][0] = *(const float4*)&Xrow[(T)*32      + lh*8]; \
        xr[(T)&1][0][1] = *(const float4*)&Xrow[(T)*32      + lh*8 + 4]; \
        xr[(T)&1][1][0] = *(const float4*)&Xrow[(T)*32 + 16 + lh*8]; \
        xr[(T)&1][1][1] = *(const float4*)&Xrow[(T)*32 + 16 + lh*8 + 4]; \
    }while(0)

#define PJ_STAGE(S,BUF) do{ \
        gload_lds16(srcp + (S)*512       + tid, &sm[BUF][wid*64]); \
        gload_lds16(srcp + (S)*512 + 256 + tid, &sm[BUF][256 + wid*64]); \
    }while(0)

#define PJ_COMP(T) do{ \
        const uint4 bq0_ = sm[(T)&3][        (pair*2  )*64 + lane]; \
        const uint4 bk0_ = sm[(T)&3][        (pair*2+1)*64 + lane]; \
        const uint4 bq1_ = sm[(T)&3][256 +   (pair*2  )*64 + lane]; \
        const uint4 bk1_ = sm[(T)&3][256 +   (pair*2+1)*64 + lane]; \
        const float4 xlo0 = xr[(T)&1][0][0], xhi0 = xr[(T)&1][0][1]; \
        const float4 xlo1 = xr[(T)&1][1][0], xhi1 = xr[(T)&1][1][1]; \
        h8 a0 = mk_h8(xlo0.x,xlo0.y,xlo0.z,xlo0.w, xhi0.x,xhi0.y,xhi0.z,xhi0.w); \
        h8 a1 = mk_h8(xlo1.x,xlo1.y,xlo1.z,xlo1.w, xhi1.x,xhi1.y,xhi1.z,xhi1.w); \
        accQ = __builtin_amdgcn_mfma_f32_32x32x16_f16(a0, __builtin_bit_cast(h8,bq0_), accQ, 0,0,0); \
        accK = __builtin_amdgcn_mfma_f32_32x32x16_f16(a0, __builtin_bit_cast(h8,bk0_), accK, 0,0,0); \
        accQ = __builtin_amdgcn_mfma_f32_32x32x16_f16(a1, __builtin_bit_cast(h8,bq1_), accQ, 0,0,0); \
        accK = __builtin_amdgcn_mfma_f32_32x32x16_f16(a1, __builtin_bit_cast(h8,bk1_), accK, 0,0,0); \
    }while(0)

    // prologue: X(0), stage 0,1,2
    PJ_XLOAD(0);
    PJ_STAGE(0,0); PJ_STAGE(1,1); PJ_STAGE(2,2);

    // iter 0 (outstanding newer-than-stage0 = s1+s2 = 4)
    WAITVM(4); SBAR();
    PJ_XLOAD(1); PJ_STAGE(3,3); PJ_COMP(0);

    // iters 1..12 (steady: s(t+1)2 + X(t)4 + s(t+2)2 = 8)
    #pragma unroll
    for (int tt=1; tt<=12; ++tt){
        WAITVM(8); SBAR();
        PJ_XLOAD(tt+1);
        PJ_STAGE(tt+3, (tt+3)&3);
        PJ_COMP(tt);
    }
    // iter 13: newer-than-s13 = s14(2)+X(13)4+s15(2) = 8
    WAITVM(8); SBAR(); PJ_XLOAD(14); PJ_COMP(13);
    // iter 14: newer-than-s14 = s15(2)+X(14)4 = 6
    WAITVM(6); SBAR(); PJ_XLOAD(15); PJ_COMP(14);
    // iter 15: newer-than-s15 = X(15)4 = 4
    WAITVM(4); SBAR(); PJ_COMP(15);

    const float bA = (pair==0 ? bq1 : bq2)[lm*R_ + lr];
    const float bB = (pair==0 ? bk1 : bk2)[lm*R_ + lr];
    unsigned short* Out = (pair==0 ? U16 : V16);
    #pragma unroll
    for (int reg=0;reg<16;reg++){
        const int row = (reg&3) + 8*(reg>>2) + 4*lh;
        const int tt  = tok0 + wtok*32 + row;
        const float val = (accQ[reg]+bA)*(accK[reg]+bB)*64.f;
        Out[((size_t)m*BT_ + tt)*R_ + lr] = f2h(val);
    }
#undef PJ_XLOAD
#undef PJ_STAGE
#undef PJ_COMP
}

// ---------------------------------------------------------------------------
// k_mqk_part: partial Mqk over a 64-token slice (scale 4096).
// grid (48, 8), block 256.
// ---------------------------------------------------------------------------
__global__ __launch_bounds__(256) void k_mqk_part(
    const unsigned short* __restrict__ U16,
    const unsigned short* __restrict__ V16,
    float* __restrict__ Mqp)
{
    const int tid = threadIdx.x;
    const int mb  = blockIdx.x;
    const int p   = blockIdx.y;
    const int t0  = p*64;

    __shared__ unsigned short Us[64][32];
    __shared__ unsigned short Vs[64][32];

    const int srow = tid>>2, sq = (tid&3)*8;
    const size_t base = (size_t)mb*T_*R_ + (size_t)(t0+srow)*R_ + sq;
    *(uint4*)&Us[srow][sq] = *(const uint4*)&U16[base];
    *(uint4*)&Vs[srow][sq] = *(const uint4*)&V16[base];
    __syncthreads();

    const int l = tid & 31;
    const int g = tid >> 5;
    float acc[4] = {0.f,0.f,0.f,0.f};
    #pragma unroll 8
    for (int tt=0; tt<64; ++tt){
        const float vv = h2f(Vs[tt][l]);
        #pragma unroll
        for (int i=0;i<4;i++) acc[i] += h2f(Us[tt][g+8*i]) * vv;
    }
    float* out = Mqp + ((size_t)p*48 + mb)*1024;
    #pragma unroll
    for (int i=0;i<4;i++) out[(g+8*i)*R_ + l] = acc[i];
}

// ---------------------------------------------------------------------------
// k_wvec_fused: reduce Mqp partials -> Ma,Mc ; P = Ma@Mc ; W16 = V16 @ P.
// grid (BT/128=64, MODS), block 256.
// ---------------------------------------------------------------------------
__global__ __launch_bounds__(256) void k_wvec_fused(
    const float* __restrict__ Mqp,
    const unsigned short* __restrict__ V16,
    unsigned short* __restrict__ W16)
{
    const int tid  = threadIdx.x;
    const int j    = blockIdx.y;
    const int tok0 = blockIdx.x * 128;
    const int b    = tok0 / T_;
    const int a = (j==0) ? 1 : 0;
    const int c = (j==2) ? 1 : 2;
    const float sc = 1.0f/(4096.0f*(float)T_);

    __shared__ float As[32][32];
    __shared__ float Cs[32][32];
    __shared__ float Ps[32][32];
    __shared__ unsigned short Vs[128][32];

    float4 sa = {0,0,0,0}, sc4 = {0,0,0,0};
    #pragma unroll
    for (int p=0;p<8;p++){
        const float4 pa = *(const float4*)&Mqp[((size_t)p*48 + a*B_+b)*1024 + tid*4];
        const float4 pc = *(const float4*)&Mqp[((size_t)p*48 + c*B_+b)*1024 + tid*4];
        sa.x+=pa.x; sa.y+=pa.y; sa.z+=pa.z; sa.w+=pa.w;
        sc4.x+=pc.x; sc4.y+=pc.y; sc4.z+=pc.z; sc4.w+=pc.w;
    }
    sa.x*=sc; sa.y*=sc; sa.z*=sc; sa.w*=sc;
    sc4.x*=sc; sc4.y*=sc; sc4.z*=sc; sc4.w*=sc;
    *(float4*)&(((float*)As)[tid*4]) = sa;
    *(float4*)&(((float*)Cs)[tid*4]) = sc4;

    // stage V while Mqp reduce is in flight
    const unsigned short* Vb = V16 + ((size_t)j*BT_ + tok0)*R_;
    #pragma unroll
    for (int e=0;e<2;e++){
        const int k = tid*2 + e;
        *(uint4*)&Vs[k>>2][(k&3)*8] = *(const uint4*)&Vb[(size_t)(k>>2)*R_ + (k&3)*8];
    }
    __syncthreads();

    const int o = tid & 31, g = tid >> 5;
    {
        float acc[4] = {0.f,0.f,0.f,0.f};
        #pragma unroll
        for (int l = 0; l < 32; ++l) {
            const float cvv = Cs[l][o];
            #pragma unroll
            for (int i = 0; i < 4; ++i) acc[i] += As[g + 8*i][l] * cvv;
        }
        #pragma unroll
        for (int i = 0; i < 4; ++i) Ps[g + 8*i][o] = acc[i];
    }
    __syncthreads();

    unsigned short* Wb = W16 + ((size_t)j*BT_ + tok0)*R_;
    #pragma unroll
    for (int i = 0; i < 16; ++i) {
        const int t = g*16 + i;
        float acc = 0.f;
        #pragma unroll
        for (int l = 0; l < 32; ++l) acc += h2f(Vs[t][l]) * Ps[l][o];
        Wb[(size_t)t*R_ + o] = f2h(acc);
    }
}

// ---------------------------------------------------------------------------
// k_gemm2_mfma v3: counted-vmcnt 4-deep pipeline, LDS-staged B.
// Block: 128 tok x 64 cols; 4 waves = (wtok 0/1) x (wcol 0/1).
// Wave = 64 tok (2 tokg) x 32 cols -> B-frag reused 2x from regs.
// K = 1024 = 32 steps of 32. Stage = 4 KB/step (1 gload inst/wave).
// grid (BT/128=64, D/64=8, MODS), block 256.
// ---------------------------------------------------------------------------
__global__ __launch_bounds__(256) void k_gemm2_mfma(
    const unsigned short* __restrict__ U16,
    const unsigned short* __restrict__ W16,
    const uint4* __restrict__ WattF, const float* __restrict__ batt,
    const float* __restrict__ xa, const float* __restrict__ xt,
    const float* __restrict__ xv,
    float* __restrict__ X, int li)
{
    __shared__ uint4 sm[4][256];      // 4 x 4KB
    const int tid = threadIdx.x;
    const int wid = tid>>6, lane = tid&63;
    const int lh = lane>>5, lr = lane&31;
    const int wtok = wid&1, wcol = wid>>1;
    const int j = blockIdx.z;
    const int tok0 = blockIdx.x*128;
    const int t0 = tok0 + wtok*64 + lr;
    const int t1 = t0 + 32;

    const uint4* src = WattF + (size_t)(li*MODS_ + j)*65536 + (size_t)blockIdx.y*256;

    union { uint4 q[4]; __fp16 h[32]; } uu0, uu1;
    {
        const uint4* Ur0 = (const uint4*)(U16 + ((size_t)j*BT_ + t0)*R_);
        const uint4* Ur1 = (const uint4*)(U16 + ((size_t)j*BT_ + t1)*R_);
        uu0.q[0]=Ur0[0]; uu0.q[1]=Ur0[1]; uu0.q[2]=Ur0[2]; uu0.q[3]=Ur0[3];
        uu1.q[0]=Ur1[0]; uu1.q[1]=Ur1[1]; uu1.q[2]=Ur1[2]; uu1.q[3]=Ur1[3];
    }
    union { uint4 q; fp16x2 p[4]; } wa0, wb0, wa1, wb1;
    {
        const uint4* Wr0 = (const uint4*)(W16 + ((size_t)j*BT_ + t0)*R_);
        const uint4* Wr1 = (const uint4*)(W16 + ((size_t)j*BT_ + t1)*R_);
        wa0.q = Wr0[lh]; wb0.q = Wr0[2+lh];
        wa1.q = Wr1[lh]; wb1.q = Wr1[2+lh];
    }

    f32x16 acc0, acc1;
    #pragma unroll
    for (int i=0;i<16;i++){ acc0[i]=0.f; acc1[i]=0.f; }

#define G2_STAGE(S,BUF) gload_lds16(src + (S)*2048 + tid, &sm[BUF][wid*64])

#define G2_COMP(T) do{ \
        const uint4 b0_ = sm[(T)&3][(wcol*2  )*64 + lane]; \
        const uint4 b1_ = sm[(T)&3][(wcol*2+1)*64 + lane]; \
        fp16x2 u0s, u1s; u0s[0]=uu0.h[T]; u0s[1]=uu0.h[T]; u1s[0]=uu1.h[T]; u1s[1]=uu1.h[T]; \
        union { h8 v; fp16x2 p[4]; } a00,a01,a10,a11; \
        _Pragma("unroll") \
        for (int q_=0;q_<4;q_++){ \
            a00.p[q_]=u0s*wa0.p[q_]; a01.p[q_]=u0s*wb0.p[q_]; \
            a10.p[q_]=u1s*wa1.p[q_]; a11.p[q_]=u1s*wb1.p[q_]; \
        } \
        acc0 = __builtin_amdgcn_mfma_f32_32x32x16_f16(a00.v, __builtin_bit_cast(h8,b0_), acc0, 0,0,0); \
        acc1 = __builtin_amdgcn_mfma_f32_32x32x16_f16(a10.v, __builtin_bit_cast(h8,b0_), acc1, 0,0,0); \
        acc0 = __builtin_amdgcn_mfma_f32_32x32x16_f16(a01.v, __builtin_bit_cast(h8,b1_), acc0, 0,0,0); \
        acc1 = __builtin_amdgcn_mfma_f32_32x32x16_f16(a11.v, __builtin_bit_cast(h8,b1_), acc1, 0,0,0); \
    }while(0)

    // prologue: stage 0,1,2  (u/w loads above are older; drained at first wait)
    G2_STAGE(0,0); G2_STAGE(1,1); G2_STAGE(2,2);

    // iters 0..29: steady vmcnt(2) = stages t+1,t+2 in flight
    #pragma unroll
    for (int tt=0; tt<30; ++tt){
        WAITVM(2); SBAR();
        if (tt < 29) G2_STAGE(tt+3, (tt+3)&3);
        G2_COMP(tt);
    }
    WAITVM(1); SBAR(); G2_COMP(30);
    WAITVM(0); SBAR(); G2_COMP(31);

    // epilogue: unscale, bias, residual
    const float* battp = batt + (size_t)(li*MODS_ + j)*D_;
    const float* Xin = (li==0) ? (j==0?xa:(j==1?xt:xv)) : (X + (size_t)j*BT_*D_);
    float* Xout = X + (size_t)j*BT_*D_;
    const float inv = 1.0f/4096.0f;
    const int d = blockIdx.y*64 + wcol*32 + lr;
    const float bt = battp[d];
    #pragma unroll
    for (int reg=0; reg<16; ++reg){
        const int row = (reg&3) + 8*(reg>>2) + 4*lh;
        const size_t xi0 = (size_t)(tok0 + wtok*64 + row)*D_ + d;
        const size_t xi1 = (size_t)(tok0 + wtok*64 + 32 + row)*D_ + d;
        const float xv0 = Xin[xi0], xv1 = Xin[xi1];
        Xout[xi0] = (acc0[reg]*inv + bt)*xv0 + BETA_*xv0;
        Xout[xi1] = (acc1[reg]*inv + bt)*xv1 + BETA_*xv1;
    }
#undef G2_STAGE
#undef G2_COMP
}

// ---------------------------------------------------------------------------
extern "C" void kernel_launch(void* const* d_in, const int* in_sizes, int n_in,
                              void* d_out, int out_size, void* d_ws, size_t ws_size,
                              hipStream_t stream)
{
    const float* x_a  = (const float*)d_in[0];
    const float* x_t  = (const float*)d_in[1];
    const float* x_v  = (const float*)d_in[2];
    const float* Wq1  = (const float*)d_in[3];
    const float* bq1  = (const float*)d_in[4];
    const float* Wq2  = (const float*)d_in[5];
    const float* bq2  = (const float*)d_in[6];
    const float* Wk1  = (const float*)d_in[7];
    const float* bk1  = (const float*)d_in[8];
    const float* Wk2  = (const float*)d_in[9];
    const float* bk2  = (const float*)d_in[10];
    const float* Watt = (const float*)d_in[11];
    const float* batt = (const float*)d_in[12];

    float* X = (float*)d_out;                        // [3][B*T][D]

    uint4* WattF  = (uint4*)d_ws;                    // 393216 u4 (6 MB)
    uint4* WprojF = WattF + 393216;                  // 49152 u4 (768 KB)
    float* Mqp    = (float*)(WprojF + 49152);        // 8*48*1024 f32 (1.5 MB)
    unsigned short* U16 = (unsigned short*)(Mqp + 393216);  // 3*BT*32 f16
    unsigned short* V16 = U16 + (size_t)MODS_*BT_*R_;
    unsigned short* W16 = V16 + (size_t)MODS_*BT_*R_;

    k_cvt<<<1728, 256, 0, stream>>>(Watt, Wq1, Wk1, Wq2, Wk2, WattF, WprojF);

    for (int li = 0; li < L_; ++li) {
        k_proj_mfma<<<dim3(BT_/64, MODS_), 256, 0, stream>>>(
            x_a, x_t, x_v, X, WprojF, bq1, bq2, bk1, bk2, U16, V16, li);
        k_mqk_part<<<dim3(MODS_*B_, 8), 256, 0, stream>>>(U16, V16, Mqp);
        k_wvec_fused<<<dim3(BT_/128, MODS_), 256, 0, stream>>>(Mqp, V16, W16);
        k_gemm2_mfma<<<dim3(BT_/128, D_/64, MODS_), 256, 0, stream>>>(
            U16, W16, WattF, batt, x_a, x_t, x_v, X, li);
    }
}